// Round 8
// baseline (881.835 us; speedup 1.0000x reference)
//
#include <hip/hip_runtime.h>
#include <math.h>

namespace {
constexpr int D     = 192;
constexpr int HW    = 256 * 512;   // 131072 = 2^17
constexpr int TOTAL = 2 * HW;      // 262144 pixels
constexpr unsigned ROWB = (unsigned)HW * 4u;   // bytes per depth slice (512 KB)
constexpr int RING_B = 8192;       // per-wave LDS ring: 32 slots x 256 B

typedef __attribute__((address_space(3))) char lds_char;

// Correctly-rounded s/5 in 3 ops (Markstein): bit-exact vs IEEE s/5.0f for
// all normal s >= 0 (our s in [0,5)).
__device__ __forceinline__ float div5(float s) {
    const float c = 0.2f;
    float q = s * c;
    float r = __builtin_fmaf(-5.0f, q, s);
    return __builtin_fmaf(r, c, q);
}

__device__ __forceinline__ bool in_range(int d, int lo, unsigned width) {
    return (unsigned)(d - lo) <= width;
}

// Streaming modal-mask state machine, bit-exact vs the numpy reference
// (identical to the verified round-0/round-7 kernel).
struct Machine {
    float bprev, maxv;
    int   index, last_fall, index_l, index_r;
    bool  r_found;

    __device__ __forceinline__ void init() {
        bprev = 1.0f;          // "ones" prepend: diff at d=0 is b0 - 1 < 0 -> fall
        maxv  = -INFINITY;
        index = 0; last_fall = 0; index_l = 0;
        index_r = D - 1;       // default: rise at virtual position D (append ones)
        r_found = false;
    }

    __device__ __forceinline__ void step(int d, float b) {
        float diff = b - bprev;
        bool fall  = diff < 0.0f;
        last_fall  = fall ? d : last_fall;               // strict fall
        bool am    = b > maxv;                           // first-occurrence argmax
        maxv       = am ? b : maxv;
        index      = am ? d : index;
        index_l    = am ? last_fall : index_l;           // last fall <= new argmax
        bool rise  = (diff > 0.0f) & (!r_found) & (!am); // first strict rise AFTER argmax
        index_r    = am ? (D - 1) : (rise ? (d - 1) : index_r);
        r_found    = am ? false : (r_found | rise);
        bprev      = b;
    }

    __device__ __forceinline__ void finish(int& lo, unsigned& wd) const {
        int r = min(index_r - index, index - index_l);
        int t = 2 * index - index_r - index_l;
        bool valid = (t > -3) && (t < 3);
        lo = valid ? index_l : (index - r);
        int hi = valid ? index_r : (index + r);
        wd = (unsigned)(hi - lo);
    }
};

// Issue the 8 HBM->LDS DMA loads of stream-chunk C (elements 8C..8C+7,
// global depth = element+2 lookahead). Depths >= D are clamped to depth 0
// (slots 30,31 of the last chunk); their values are statically zeroed in
// compute, matching the reference's zero-padding. LDS dest is wave-uniform
// base + lane*4 (global_load_lds HW rule); source is per-lane.
template<int C>
__device__ __forceinline__ void issue8(const char* colb, lds_char* ldsb) {
    #pragma unroll
    for (int j = 0; j < 8; ++j) {
        const int      el = 8 * C + j;
        const int      gi = el + 2;
        const unsigned bo = (gi < D) ? (unsigned)gi * ROWB : 0u;
        __builtin_amdgcn_global_load_lds(
            (__attribute__((address_space(1))) void*)(colb + bo),
            (__attribute__((address_space(3))) void*)(ldsb + ((el & 31) << 8)),
            4, 0, 0);
    }
}

// One atomic asm block per chunk: counted vmcnt wait (chunk's 8 DMA loads
// landed; 3 younger chunks = 24 stay in flight), 8 ds_read_b32, lgkmcnt(0).
// Single block => the compiler cannot hoist consumers between the reads and
// the waits (outputs only become available after the whole block). "=&v"
// early-clobber keeps outputs off the vaddr input.
#define DS_RW(VM, O0,O1,O2,O3,O4,O5,O6,O7, B, VA)                         \
    asm volatile("s_waitcnt vmcnt(" #VM ")\n\t"                           \
                 "ds_read_b32 %0, %8 offset:" #O0 "\n\t"                  \
                 "ds_read_b32 %1, %8 offset:" #O1 "\n\t"                  \
                 "ds_read_b32 %2, %8 offset:" #O2 "\n\t"                  \
                 "ds_read_b32 %3, %8 offset:" #O3 "\n\t"                  \
                 "ds_read_b32 %4, %8 offset:" #O4 "\n\t"                  \
                 "ds_read_b32 %5, %8 offset:" #O5 "\n\t"                  \
                 "ds_read_b32 %6, %8 offset:" #O6 "\n\t"                  \
                 "ds_read_b32 %7, %8 offset:" #O7 "\n\t"                  \
                 "s_waitcnt lgkmcnt(0)"                                   \
                 : "=&v"(B[0]), "=&v"(B[1]), "=&v"(B[2]), "=&v"(B[3]),    \
                   "=&v"(B[4]), "=&v"(B[5]), "=&v"(B[6]), "=&v"(B[7])     \
                 : "v"(VA) : "memory")

#define RD0(VM,B,VA) DS_RW(VM,    0, 256, 512, 768,1024,1280,1536,1792,B,VA)
#define RD1(VM,B,VA) DS_RW(VM, 2048,2304,2560,2816,3072,3328,3584,3840,B,VA)
#define RD2(VM,B,VA) DS_RW(VM, 4096,4352,4608,4864,5120,5376,5632,5888,B,VA)
#define RD3(VM,B,VA) DS_RW(VM, 6144,6400,6656,6912,7168,7424,7936-256,7936,B,VA)

// 24 chunks (192 lookahead elements), 4-chunk LDS ring: constant THREE-chunk
// load->use distance (~24 steps of VALU in flight), vs 2 chunks in the VGPR
// version -- and no VGPR data buffers at all, sidestepping the 64-VGPR wall
// that killed rounds 2/4/5. Per-wave private ring => no barriers.
template<typename F>
__device__ __forceinline__ void stream_ring(const char* colb, lds_char* ldsb,
                                            unsigned va, F&& f) {
    float B[8];
    int d = 0;
    auto comp = [&]() {
        #pragma unroll
        for (int j = 0; j < 8; ++j) {
            float xv = B[j];
            if (d >= 190) xv = 0.0f;   // clamped tail slots -> reference zeros
            f(d, xv);
            ++d;
        }
    };
    issue8<0>(colb, ldsb); issue8<1>(colb, ldsb);
    issue8<2>(colb, ldsb); issue8<3>(colb, ldsb);
    RD0(24,B,va); comp(); issue8< 4>(colb, ldsb);
    RD1(24,B,va); comp(); issue8< 5>(colb, ldsb);
    RD2(24,B,va); comp(); issue8< 6>(colb, ldsb);
    RD3(24,B,va); comp(); issue8< 7>(colb, ldsb);
    RD0(24,B,va); comp(); issue8< 8>(colb, ldsb);
    RD1(24,B,va); comp(); issue8< 9>(colb, ldsb);
    RD2(24,B,va); comp(); issue8<10>(colb, ldsb);
    RD3(24,B,va); comp(); issue8<11>(colb, ldsb);
    RD0(24,B,va); comp(); issue8<12>(colb, ldsb);
    RD1(24,B,va); comp(); issue8<13>(colb, ldsb);
    RD2(24,B,va); comp(); issue8<14>(colb, ldsb);
    RD3(24,B,va); comp(); issue8<15>(colb, ldsb);
    RD0(24,B,va); comp(); issue8<16>(colb, ldsb);
    RD1(24,B,va); comp(); issue8<17>(colb, ldsb);
    RD2(24,B,va); comp(); issue8<18>(colb, ldsb);
    RD3(24,B,va); comp(); issue8<19>(colb, ldsb);
    RD0(24,B,va); comp(); issue8<20>(colb, ldsb);
    RD1(24,B,va); comp(); issue8<21>(colb, ldsb);
    RD2(24,B,va); comp(); issue8<22>(colb, ldsb);
    RD3(24,B,va); comp(); issue8<23>(colb, ldsb);
    RD0(24,B,va); comp();            // c=20, nothing left to issue
    RD1(16,B,va); comp();            // c=21: 16 outstanding behind it
    RD2( 8,B,va); comp();            // c=22
    RD3( 0,B,va); comp();            // c=23: full drain inside the block
}
} // namespace

extern "C" __global__ void __launch_bounds__(256, 4)
dme_kernel(const float* __restrict__ x, float* __restrict__ out)
{
    __shared__ char ring[4 * RING_B];          // 32 KB: 8 KB private per wave

    // n is block-uniform: 512 blocks per image -> base pointer lives in SGPRs.
    const int n  = blockIdx.x >> 9;
    const int hw = ((blockIdx.x & 511) << 8) | threadIdx.x;
    const float* __restrict__ xn = x + (size_t)n * (size_t)(D * HW);
    const char* colb = (const char*)xn + (unsigned)hw * 4u;  // per-lane byte base

    const int wid  = threadIdx.x >> 6;
    const int lane = threadIdx.x & 63;
    lds_char* ldsb = (lds_char*)&ring[wid * RING_B];         // wave-uniform
    const unsigned va = (unsigned)(size_t)ldsb + (unsigned)lane * 4u;

    const float x0 = *(const float*)colb;
    const float x1 = *(const float*)(colb + ROWB);

    // ================= pass 1: modal mask of blur(x) =================
    Machine m1; m1.init();
    {
        float w0 = 0.f, w1 = 0.f, w2 = x0, w3 = x1;
        stream_ring(colb, ldsb, va, [&](int d, float xv) {
            // exact left-to-right window sum, matching reference add order
            float s = w0 + w1; s += w2; s += w3; s += xv;
            m1.step(d, div5(s));
            w0 = w1; w1 = w2; w2 = w3; w3 = xv;
        });
    }
    int lo1; unsigned wd1; m1.finish(lo1, wd1);

    // ============ pass 2: modal mask of blur(x)*~mask1 ============
    Machine m2; m2.init();
    {
        float w0 = 0.f, w1 = 0.f, w2 = x0, w3 = x1;
        stream_ring(colb, ldsb, va, [&](int d, float xv) {
            float s = w0 + w1; s += w2; s += w3; s += xv;
            float b = div5(s);
            bool in1 = in_range(d, lo1, wd1);
            m2.step(d, in1 ? 0.0f : b);          // x_blur2 = x_blur * ~mask1
            w0 = w1; w1 = w2; w2 = w3; w3 = xv;
        });
    }
    int lo2; unsigned wd2; m2.finish(lo2, wd2);

    // ======= y-sums over [lo1, hi1] (y = x*mask1), exact interval fold ====
    // Same IEEE identity as pass 3: the reference's jnp.sum adds exact zeros
    // outside the interval; skipping them in ascending d order is bit-exact.
    float sum_y = 0.f, wsum_y = 0.f;
    {
        const int dend = lo1 + (int)wd1;
        for (int dd = lo1; dd <= dend; ++dd) {
            float xv = *(const float*)(colb + (unsigned)dd * ROWB);
            sum_y += xv;
            wsum_y = __builtin_fmaf(xv, (float)dd, wsum_y);
        }
    }

    // ========= pass 3: z-sums (z = x * ~mask1 * mask2nd) =========
    float sum_z = 0.f, wsum_z = 0.f;
    {
        const int dend = lo2 + (int)wd2;
        for (int dd = lo2; dd <= dend; ++dd) {
            float xv = *(const float*)(colb + (unsigned)dd * ROWB);
            bool  zz = !in_range(dd, lo1, wd1);
            float xm = zz ? xv : 0.0f;
            sum_z += xm;
            wsum_z = __builtin_fmaf(xm, (float)dd, wsum_z);
        }
    }

    bool  v = (sum_y >= sum_z);
    float S = v ? sum_y  : sum_z;
    float W = v ? wsum_y : wsum_z;
    out[hw + n * HW] = W / S;    // == sum(xm*d)/sum(xm)
}

extern "C" void kernel_launch(void* const* d_in, const int* in_sizes, int n_in,
                              void* d_out, int out_size, void* d_ws, size_t ws_size,
                              hipStream_t stream)
{
    const float* x   = (const float*)d_in[0];
    float*       out = (float*)d_out;
    dim3 block(256), grid(TOTAL / 256);          // 1024 blocks, 16 waves/CU
    hipLaunchKernelGGL(dme_kernel, grid, block, 0, stream, x, out);
}

// Round 9
// 315.794 us; speedup vs baseline: 2.7924x; 2.7924x over previous
//
#include <hip/hip_runtime.h>
#include <math.h>

namespace {
constexpr int D     = 192;
constexpr int HW    = 256 * 512;   // 131072 = 2^17
constexpr int TOTAL = 2 * HW;      // 262144 pixels

// Correctly-rounded s/5 in 3 ops (Markstein): bit-exact vs IEEE s/5.0f for
// all normal s >= 0 (our s in [0,5)).
__device__ __forceinline__ float div5(float s) {
    const float c = 0.2f;
    float q = s * c;
    float r = __builtin_fmaf(-5.0f, q, s);
    return __builtin_fmaf(r, c, q);
}

__device__ __forceinline__ bool in_range(int d, int lo, unsigned width) {
    return (unsigned)(d - lo) <= width;
}

// Streaming modal-mask state machine, bit-exact vs the numpy reference.
// (Identical to the verified round-0/round-7 kernel.)
struct Machine {
    float bprev, maxv;
    int   index, last_fall, index_l, index_r;
    bool  r_found;

    __device__ __forceinline__ void init() {
        bprev = 1.0f;          // "ones" prepend: diff at d=0 is b0 - 1 < 0 -> fall
        maxv  = -INFINITY;
        index = 0; last_fall = 0; index_l = 0;
        index_r = D - 1;       // default: rise at virtual position D (append ones)
        r_found = false;
    }

    __device__ __forceinline__ void step(int d, float b) {
        float diff = b - bprev;
        bool fall  = diff < 0.0f;
        last_fall  = fall ? d : last_fall;               // strict fall
        bool am    = b > maxv;                           // first-occurrence argmax
        maxv       = am ? b : maxv;
        index      = am ? d : index;
        index_l    = am ? last_fall : index_l;           // last fall <= new argmax
        bool rise  = (diff > 0.0f) & (!r_found) & (!am); // first strict rise AFTER argmax
        index_r    = am ? (D - 1) : (rise ? (d - 1) : index_r);
        r_found    = am ? false : (r_found | rise);
        bprev      = b;
    }

    __device__ __forceinline__ void finish(int& lo, unsigned& wd) const {
        int r = min(index_r - index, index - index_l);
        int t = 2 * index - index_r - index_l;
        bool valid = (t > -3) && (t < 3);
        lo = valid ? index_l : (index - r);
        int hi = valid ? index_r : (index + r);
        wd = (unsigned)(hi - lo);
    }
};

// OFS=2: chunk c supplies x[8c+2+j] (the d+2 lookahead for the blur window).
template<int OFS>
__device__ __forceinline__ void loadc(const float* __restrict__ col, int c,
                                      float (&buf)[8]) {
    #pragma unroll
    for (int j = 0; j < 8; ++j)
        buf[j] = col[(size_t)(8 * c + OFS + j) * HW];
}
template<int OFS>
__device__ __forceinline__ void loadc_guard(const float* __restrict__ col, int c,
                                            float (&buf)[8]) {
    #pragma unroll
    for (int j = 0; j < 8; ++j) {
        int idx = 8 * c + OFS + j;
        buf[j] = (idx < D) ? col[(size_t)idx * HW] : 0.0f;
    }
}

// 24 chunks of 8 depths, 3-buffer rotating software pipeline with a constant
// TWO-chunk load->use distance. This is the verified round-0/7 configuration:
// 64 VGPR, zero scratch. Session ledger -- do NOT revisit:
//   * deeper VGPR pipelines (6-buffer): allocator hard-refuses >64 VGPR
//     (launch_bounds(256,4), waves_per_eu(4,4) both failed; 290 MB scratch)
//   * more waves (pixel-split, 2x grid): 2.1 -> 1.35 TB/s, slower (R2/R3)
//   * LDS ring + counted vmcnt (global_load_lds): 916 MB fetch, 695 us (R8)
template<int OFS, typename F>
__device__ __forceinline__ void stream24(const float* __restrict__ col, F&& f) {
    float A[8], B[8], C[8];
    loadc<OFS>(col, 0, A);
    loadc<OFS>(col, 1, B);
    loadc<OFS>(col, 2, C);
    int d = 0;
    auto comp = [&](float (&buf)[8]) {
        #pragma unroll
        for (int j = 0; j < 8; ++j) { f(d, buf[j]); ++d; }
    };
    for (int g = 0; g < 6; ++g) {          // chunks 3g..3g+2, issue 3g+3..3g+5
        comp(A); loadc<OFS>(col, 3 * g + 3, A);
        comp(B); loadc<OFS>(col, 3 * g + 4, B);
        comp(C); loadc<OFS>(col, 3 * g + 5, C);
    }
    // g == 6: computes 18..20, issues 21,22 plain; 23 needs the OOB guard
    // only in lookahead mode (indices 186..193; 192,193 -> 0).
    comp(A); loadc<OFS>(col, 21, A);
    comp(B); loadc<OFS>(col, 22, B);
    comp(C);
    if (OFS == 2) loadc_guard<OFS>(col, 23, C);
    else          loadc<OFS>(col, 23, C);
    // g == 7: drain
    comp(A); comp(B); comp(C);
}
} // namespace

extern "C" __global__ void __launch_bounds__(256, 4)
dme_kernel(const float* __restrict__ x, float* __restrict__ out)
{
    // n is block-uniform: 512 blocks per image -> base pointer lives in SGPRs.
    const int n  = blockIdx.x >> 9;
    const int hw = ((blockIdx.x & 511) << 8) | threadIdx.x;
    const float* __restrict__ col = x + (size_t)n * (size_t)(D * HW) + hw;

    const float x0 = col[0];
    const float x1 = col[HW];

    // ================= pass 1: modal mask of blur(x) =================
    Machine m1; m1.init();
    {
        float w0 = 0.f, w1 = 0.f, w2 = x0, w3 = x1;
        stream24<2>(col, [&](int d, float xv) {
            // exact left-to-right window sum, matching reference add order
            float s = w0 + w1; s += w2; s += w3; s += xv;
            m1.step(d, div5(s));
            w0 = w1; w1 = w2; w2 = w3; w3 = xv;
        });
    }
    int lo1; unsigned wd1; m1.finish(lo1, wd1);

    // ====== pass 2: modal mask of blur(x)*~mask1, plus y-sums ======
    Machine m2; m2.init();
    float sum_y = 0.f, wsum_y = 0.f;
    {
        float w0 = 0.f, w1 = 0.f, w2 = x0, w3 = x1;
        float fd = 0.0f;
        stream24<2>(col, [&](int d, float xv) {
            float s = w0 + w1; s += w2; s += w3; s += xv;
            float b = div5(s);
            bool in1 = in_range(d, lo1, wd1);
            m2.step(d, in1 ? 0.0f : b);          // x_blur2 = x_blur * ~mask1
            float xm = in1 ? w2 : 0.f;           // y = x*mask1; x[d] == w2
            sum_y += xm;
            wsum_y = __builtin_fmaf(xm, fd, wsum_y);  // fma(0,fd,w)==w exact
            w0 = w1; w1 = w2; w2 = w3; w3 = xv; fd += 1.0f;
        });
    }
    int lo2; unsigned wd2; m2.finish(lo2, wd2);

    // ========= pass 3: z-sums (z = x * ~mask1 * mask2nd) =========
    // z[d] == 0 outside [lo2, lo2+wd2]; the reference's jnp.sum adds those
    // zeros, and acc + 0.0f is an exact IEEE identity for our non-negative
    // accumulators -- so folding ONLY the in-interval depths in ascending d
    // order is bit-identical to the full 192-depth fold. [lo2,hi2] is
    // provably within [0, D-1] (finish() algebra).
    //
    // 4-wide load batching: issue 4 independent loads back-to-back, then do
    // the 4 accumulations serially IN ASCENDING ORDER (bit-exact: identical
    // add sequence). The R7 version paid full L3 latency (~500 cyc) per
    // depth on a serial load->add chain; this pays it once per 4 depths.
    float sum_z = 0.f, wsum_z = 0.f;
    {
        const int dend = lo2 + (int)wd2;       // inclusive
        auto acc = [&](float xv, int dd) {
            bool  zz = !in_range(dd, lo1, wd1);
            float xm = zz ? xv : 0.0f;
            sum_z += xm;
            wsum_z = __builtin_fmaf(xm, (float)dd, wsum_z);
        };
        int dd = lo2;
        for (; dd + 3 <= dend; dd += 4) {
            float v0 = col[(size_t)(dd + 0) * HW];
            float v1 = col[(size_t)(dd + 1) * HW];
            float v2 = col[(size_t)(dd + 2) * HW];
            float v3 = col[(size_t)(dd + 3) * HW];
            acc(v0, dd + 0); acc(v1, dd + 1);
            acc(v2, dd + 2); acc(v3, dd + 3);
        }
        for (; dd <= dend; ++dd) acc(col[(size_t)dd * HW], dd);
    }

    bool  v = (sum_y >= sum_z);
    float S = v ? sum_y  : sum_z;
    float W = v ? wsum_y : wsum_z;
    out[hw + n * HW] = W / S;    // == sum(xm*d)/sum(xm)
}

extern "C" void kernel_launch(void* const* d_in, const int* in_sizes, int n_in,
                              void* d_out, int out_size, void* d_ws, size_t ws_size,
                              hipStream_t stream)
{
    const float* x   = (const float*)d_in[0];
    float*       out = (float*)d_out;
    dim3 block(256), grid(TOTAL / 256);          // 1024 blocks, 16 waves/CU
    hipLaunchKernelGGL(dme_kernel, grid, block, 0, stream, x, out);
}